// Round 1
// baseline (7288.910 us; speedup 1.0000x reference)
//
#include <hip/hip_runtime.h>

typedef _Float16 hf;
typedef _Float16 hf2 __attribute__((ext_vector_type(2)));
typedef _Float16 hf4 __attribute__((ext_vector_type(4)));
typedef _Float16 hf8 __attribute__((ext_vector_type(8)));

#define NTH 512
#define SMEM_BYTES 150848

// ---------- helpers ----------
__device__ __forceinline__ float fdot2f(hf2 a, hf2 b, float c){
#if __has_builtin(__builtin_amdgcn_fdot2)
  return __builtin_amdgcn_fdot2(a, b, c, false);
#else
  return c + (float)a[0]*(float)b[0] + (float)a[1]*(float)b[1];
#endif
}

__device__ __forceinline__ float dsilu(float x){ return x / (1.f + __expf(-x)); }

__device__ __forceinline__ float dtanh(float x){
  float xc = fminf(fmaxf(x, -10.f), 10.f);
  float e = __expf(2.f * xc);
  return (e - 1.f) / (e + 1.f);
}

__device__ __forceinline__ hf2 pick8(hf8 v, int j){ hf2 r; r[0] = v[2*j]; r[1] = v[2*j+1]; return r; }
__device__ __forceinline__ hf2 pick4(hf4 v, int j){ hf2 r; r[0] = v[2*j]; r[1] = v[2*j+1]; return r; }

// stage W[row0+k][col0+c] (k<nrows, c<ncols) as half2 k-pairs: wp halfindex = (k/2)*2*ncols + 2c + (k&1)
__device__ __forceinline__ void stage_pairs(hf* wp, const float* W, int ldw, int row0, int nrows,
                                            int col0, int ncols, int tid){
  int total = nrows * ncols;
  for (int idx = tid; idx < total; idx += NTH){
    int k = idx / ncols;
    int c = idx - k * ncols;
    wp[(k >> 1) * (2 * ncols) + 2 * c + (k & 1)] = (hf)W[(row0 + k) * ldw + col0 + c];
  }
}

// qkv slice for head hh: ncols=96 -> c<32: q col hh*32+c ; 32..63: 128+hh*32 ; 64..95: 256+hh*32
__device__ __forceinline__ void stage_pairs_qkv(hf* wp, const float* W, int hh, int tid){
  for (int idx = tid; idx < 128 * 96; idx += NTH){
    int k = idx / 96;
    int c = idx - k * 96;
    int gcol = (c >> 5) * 128 + hh * 32 + (c & 31);
    wp[(k >> 1) * 192 + 2 * c + (k & 1)] = (hf)W[k * 384 + gcol];
  }
}

// acc[8][4] += A[rb..rb+7][kA0..kA0+K) * Wp(cols cb..cb+3)
__device__ __forceinline__ void gemm_acc(float (&acc)[8][4], const hf* A, int lda, int kA0, int K,
                                         const hf* wp, int PN, int rb, int cb){
  for (int k4 = 0; k4 < K; k4 += 4){
    const hf* w0p = wp + (k4 >> 1) * (2 * PN) + (cb << 1);
    hf8 w0 = *(const hf8*)(w0p);
    hf8 w1 = *(const hf8*)(w0p + 2 * PN);
#pragma unroll
    for (int i = 0; i < 8; ++i){
      hf4 a = *(const hf4*)(A + (rb + i) * lda + kA0 + k4);
      hf2 a01 = pick4(a, 0);
      hf2 a23 = pick4(a, 1);
#pragma unroll
      for (int j = 0; j < 4; ++j){
        acc[i][j] = fdot2f(a01, pick8(w0, j), acc[i][j]);
        acc[i][j] = fdot2f(a23, pick8(w1, j), acc[i][j]);
      }
    }
  }
}

// LayerNorm epilogue: acc holds (resid+bias) values for rows rb..rb+7, cols cb..cb+3.
// Thread layout t = rg*32 + cg: 32 consecutive lanes share the same 8 rows.
__device__ __forceinline__ void ln_write(float (&acc)[8][4], hf* Hh, int rb, int cb,
                                         const float* g, const float* bb){
  float ps[8], pq[8];
#pragma unroll
  for (int i = 0; i < 8; ++i){
    ps[i] = acc[i][0] + acc[i][1] + acc[i][2] + acc[i][3];
    pq[i] = acc[i][0]*acc[i][0] + acc[i][1]*acc[i][1] + acc[i][2]*acc[i][2] + acc[i][3]*acc[i][3];
  }
#pragma unroll
  for (int st = 0; st < 5; ++st){
    int msk = 1 << st;
#pragma unroll
    for (int i = 0; i < 8; ++i){
      ps[i] += __shfl_xor(ps[i], msk);
      pq[i] += __shfl_xor(pq[i], msk);
    }
  }
#pragma unroll
  for (int i = 0; i < 8; ++i){
    float mean = ps[i] * (1.f/128.f);
    float var  = pq[i] * (1.f/128.f) - mean * mean;
    float rstd = rsqrtf(var + 1e-5f);
#pragma unroll
    for (int j = 0; j < 4; ++j){
      int c = cb + j;
      Hh[(rb + i) * 132 + c] = (hf)((acc[i][j] - mean) * rstd * g[c] + bb[c]);
    }
  }
}

// ---------- fused kernel: one block per batch element ----------
__global__ __launch_bounds__(NTH) void fused_fp(
    const float* __restrict__ x, const int* __restrict__ timesteps, const float* __restrict__ cond,
    const float* __restrict__ t_w1, const float* __restrict__ t_b1,
    const float* __restrict__ t_w2, const float* __restrict__ t_b2,
    const float* __restrict__ c_w1, const float* __restrict__ c_b1,
    const float* __restrict__ c_w2, const float* __restrict__ c_b2,
    const float* __restrict__ wqkv_g, const float* __restrict__ bqkv_g,
    const float* __restrict__ wo_g, const float* __restrict__ bo_g,
    const float* __restrict__ ln1g_g, const float* __restrict__ ln1b_g,
    const float* __restrict__ fw1_g, const float* __restrict__ fb1_g,
    const float* __restrict__ fw2_g, const float* __restrict__ fb2_g,
    const float* __restrict__ ln2g_g, const float* __restrict__ ln2b_g,
    const float* __restrict__ mw_w1, const float* __restrict__ mw_b1,
    const float* __restrict__ mw_w2, const float* __restrict__ mw_b2,
    const float* __restrict__ s_w1, const float* __restrict__ s_b1,
    const float* __restrict__ s_w2, const float* __restrict__ s_b2,
    float* __restrict__ out)
{
  extern __shared__ char smem[];
  hf* Hh = (hf*)(smem);                    // [128][132] halfs
  hf* WP = (hf*)(smem + 33792);            // 16384 halfs (pair-packed weights)
  char* SCR = smem + 66560;                // 66560-byte union region
  hf* QB = (hf*)(SCR);                     // [128][40]
  hf* KB = (hf*)(SCR + 10240);             // [128][40]
  hf* VB = (hf*)(SCR + 20480);             // [128][40]
  hf* OB = (hf*)(SCR + 30720);             // [128][132]
  hf* H1 = (hf*)(SCR);                     // [128][68]   (cond phase)
  hf* F1 = (hf*)(SCR);                     // [128][260]  (ffn phase)
  float* MISC = (float*)(smem + 133120);
  float* te   = MISC;          // 128
  float* th   = MISC + 128;    // 256
  float* comb = MISC + 384;    // 256
  float* cvec = MISC + 640;    // 512
  float* sw01 = MISC + 1152;   // 1024 (s_w1 rows 0 and 1, [2][4][128])
  float* sw2s = MISC + 2176;   // 1024
  float* mwls = MISC + 3200;   // 16 (mw[0..3], logits[4..7])
  float* cst  = MISC + 3216;   // 768 (conditions)
  float* cw1s = MISC + 3984;   // 448 (c_w1 384 + c_b1 64)

  const int b = blockIdx.x;
  const int t = threadIdx.x;

  // ---- Phase 0: time-embedding features + cond staging ----
  if (t < 128){
    int i = t & 63;
    float f = __expf(-logf(10000.f) * (float)i * (1.f/64.f));
    float a = (float)timesteps[b] * f;
    te[t] = (t < 64) ? cosf(a) : sinf(a);
  }
  for (int idx = t; idx < 768; idx += NTH) cst[idx] = cond[b * 768 + idx];
  for (int idx = t; idx < 384; idx += NTH) cw1s[idx] = c_w1[idx];
  if (t < 64) cw1s[384 + t] = c_b1[t];
  __syncthreads();

  // time MLP hidden (256) ; cond MLP layer1 -> H1 [128][64]
  if (t < 256){
    float a = t_b1[t];
    for (int i = 0; i < 128; ++i) a += te[i] * t_w1[i * 256 + t];
    th[t] = dsilu(a);
  }
  for (int idx = t; idx < 8192; idx += NTH){
    int s = idx >> 6, j = idx & 63;
    float a = cw1s[384 + j];
#pragma unroll
    for (int cc = 0; cc < 6; ++cc) a += cst[s * 6 + cc] * cw1s[cc * 64 + j];
    H1[s * 68 + j] = (hf)dsilu(a);
  }
  __syncthreads();

  // time MLP out -> comb[0:128] ; stage c_w2 pairs
  if (t < 128){
    float a = t_b2[t];
    for (int j = 0; j < 256; ++j) a += th[j] * t_w2[j * 128 + t];
    comb[t] = a;
  }
  stage_pairs(WP, c_w2, 128, 0, 64, 0, 128, t);
  __syncthreads();

  // cond MLP layer2 -> Hh
  {
    int rg = t >> 5, cg = t & 31, rb = rg * 8, cb = cg * 4;
    float acc[8][4] = {};
    gemm_acc(acc, H1, 68, 0, 64, WP, 128, rb, cb);
#pragma unroll
    for (int i = 0; i < 8; ++i)
#pragma unroll
      for (int j = 0; j < 4; ++j){
        int c = cb + j;
        Hh[(rb + i) * 132 + c] = (hf)dsilu(acc[i][j] + c_b2[c]);
      }
  }
  __syncthreads();

  // ---- 2 transformer layers ----
  for (int l = 0; l < 2; ++l){
    const float* Wqkv = wqkv_g + l * 49152;
    const float* Bqkv = bqkv_g + l * 384;
    const float* Wo   = wo_g   + l * 16384;
    const float* Bo   = bo_g   + l * 128;
    const float* L1g  = ln1g_g + l * 128;
    const float* L1b  = ln1b_g + l * 128;
    const float* Fw1  = fw1_g  + l * 32768;
    const float* Fb1  = fb1_g  + l * 256;
    const float* Fw2  = fw2_g  + l * 32768;
    const float* Fb2  = fb2_g  + l * 128;
    const float* L2g  = ln2g_g + l * 128;
    const float* L2b  = ln2b_g + l * 128;

    // attention, head by head
    for (int hh = 0; hh < 4; ++hh){
      stage_pairs_qkv(WP, Wqkv, hh, t);
      __syncthreads();
      if (t < 384){
        int rg = t / 24, cg = t - rg * 24, rb = rg * 8, cb = cg * 4;
        float acc[8][4] = {};
        gemm_acc(acc, Hh, 132, 0, 128, WP, 96, rb, cb);
#pragma unroll
        for (int i = 0; i < 8; ++i)
#pragma unroll
          for (int j = 0; j < 4; ++j){
            int c = cb + j, sel = c >> 5, cc = c & 31;
            float v = acc[i][j] + Bqkv[sel * 128 + hh * 32 + cc];
            if (sel == 0)      QB[(rb + i) * 40 + cc] = (hf)(v * 0.17677669529663687f);
            else if (sel == 1) KB[(rb + i) * 40 + cc] = (hf)v;
            else               VB[(rb + i) * 40 + cc] = (hf)v;
          }
      }
      __syncthreads();
      // attention: thread = (row r, quarter qa); kpos = 4*i + qa (interleaved, bank-friendly)
      {
        int r = t >> 2, qa = t & 3;
        hf8 qv[4];
#pragma unroll
        for (int u = 0; u < 4; ++u) qv[u] = *(const hf8*)(QB + r * 40 + u * 8);
        float s[32];
#pragma unroll
        for (int i = 0; i < 32; ++i){
          int kp = 4 * i + qa;
          float a = 0.f;
#pragma unroll
          for (int u = 0; u < 4; ++u){
            hf8 kv = *(const hf8*)(KB + kp * 40 + u * 8);
#pragma unroll
            for (int p = 0; p < 4; ++p) a = fdot2f(pick8(qv[u], p), pick8(kv, p), a);
          }
          s[i] = a;
        }
        float m = -1e30f;
#pragma unroll
        for (int i = 0; i < 32; ++i) m = fmaxf(m, s[i]);
        m = fmaxf(m, __shfl_xor(m, 1));
        m = fmaxf(m, __shfl_xor(m, 2));
        float lsum = 0.f;
#pragma unroll
        for (int i = 0; i < 32; ++i){ s[i] = __expf(s[i] - m); lsum += s[i]; }
        lsum += __shfl_xor(lsum, 1);
        lsum += __shfl_xor(lsum, 2);
        float o[32];
#pragma unroll
        for (int j = 0; j < 32; ++j) o[j] = 0.f;
#pragma unroll
        for (int i = 0; i < 32; ++i){
          int kp = 4 * i + qa;
          float p = s[i];
#pragma unroll
          for (int u = 0; u < 4; ++u){
            hf8 vv = *(const hf8*)(VB + kp * 40 + u * 8);
#pragma unroll
            for (int e = 0; e < 8; ++e) o[u * 8 + e] += p * (float)vv[e];
          }
        }
#pragma unroll
        for (int j = 0; j < 32; ++j){
          o[j] += __shfl_xor(o[j], 1);
          o[j] += __shfl_xor(o[j], 2);
        }
        float rl = 1.f / lsum;
#pragma unroll
        for (int e = 0; e < 8; ++e)
          OB[r * 132 + hh * 32 + qa * 8 + e] = (hf)(o[qa * 8 + e] * rl);
      }
      __syncthreads();
    }

    // output proj + residual + LN1
    stage_pairs(WP, Wo, 128, 0, 128, 0, 128, t);
    __syncthreads();
    {
      int rg = t >> 5, cg = t & 31, rb = rg * 8, cb = cg * 4;
      float acc[8][4] = {};
      gemm_acc(acc, OB, 132, 0, 128, WP, 128, rb, cb);
#pragma unroll
      for (int i = 0; i < 8; ++i)
#pragma unroll
        for (int j = 0; j < 4; ++j){
          int c = cb + j;
          acc[i][j] += Bo[c] + (float)Hh[(rb + i) * 132 + c];
        }
      ln_write(acc, Hh, rb, cb, L1g, L1b);
    }
    __syncthreads();

    // FFN1 (relu), two 128-col chunks
    for (int ch = 0; ch < 2; ++ch){
      stage_pairs(WP, Fw1, 256, 0, 128, ch * 128, 128, t);
      __syncthreads();
      int rg = t >> 5, cg = t & 31, rb = rg * 8, cb = cg * 4;
      float acc[8][4] = {};
      gemm_acc(acc, Hh, 132, 0, 128, WP, 128, rb, cb);
#pragma unroll
      for (int i = 0; i < 8; ++i)
#pragma unroll
        for (int j = 0; j < 4; ++j){
          int c = cb + j;
          float v = acc[i][j] + Fb1[ch * 128 + c];
          F1[(rb + i) * 260 + ch * 128 + c] = (hf)fmaxf(v, 0.f);
        }
      __syncthreads();
    }
    // FFN2: K=256 in two K-chunks, acc persists; then residual + LN2
    {
      int rg = t >> 5, cg = t & 31, rb = rg * 8, cb = cg * 4;
      float acc[8][4] = {};
      for (int ch = 0; ch < 2; ++ch){
        stage_pairs(WP, Fw2, 128, ch * 128, 128, 0, 128, t);
        __syncthreads();
        gemm_acc(acc, F1, 260, ch * 128, 128, WP, 128, rb, cb);
        __syncthreads();
      }
#pragma unroll
      for (int i = 0; i < 8; ++i)
#pragma unroll
        for (int j = 0; j < 4; ++j){
          int c = cb + j;
          acc[i][j] += Fb2[c] + (float)Hh[(rb + i) * 132 + c];
        }
      ln_write(acc, Hh, rb, cb, L2g, L2b);
    }
    __syncthreads();
  }

  // ---- cond_emb mean -> comb[128:256] ----
  if (t < 128){
    float a = 0.f;
    for (int s2 = 0; s2 < 128; ++s2) a += (float)Hh[s2 * 132 + t];
    comb[128 + t] = a * (1.f/128.f);
  }
  __syncthreads();

  // mixture hidden + stage student weights
  if (t < 128){
    float a = mw_b1[t];
    for (int i = 0; i < 256; ++i) a += comb[i] * mw_w1[i * 128 + t];
    th[t] = dsilu(a);
  }
  {
    int k = t >> 7, j = t & 127;
    sw01[t]       = s_w1[k * 33024 + j];         // row 0 (x0 coeff)
    sw01[512 + t] = s_w1[k * 33024 + 128 + j];   // row 1 (x1 coeff)
  }
  for (int idx = t; idx < 1024; idx += NTH) sw2s[idx] = s_w2[idx];
  __syncthreads();

  if (t < 4){
    float a = mw_b2[t];
    for (int j = 0; j < 128; ++j) a += th[j] * mw_w2[j * 4 + t];
    mwls[4 + t] = a;
  }
  __syncthreads();
  if (t == 0){
    float mx = fmaxf(fmaxf(mwls[4], mwls[5]), fmaxf(mwls[6], mwls[7]));
    float e0 = __expf(mwls[4] - mx), e1 = __expf(mwls[5] - mx);
    float e2 = __expf(mwls[6] - mx), e3 = __expf(mwls[7] - mx);
    float rs = 1.f / (e0 + e1 + e2 + e3);
    mwls[0] = e0 * rs; mwls[1] = e1 * rs; mwls[2] = e2 * rs; mwls[3] = e3 * rs;
  }
  // cvec[k][j] = s_b1 + combined . s_w1[k, 2:, j]   (s-independent part of student layer1)
  {
    int k = t >> 7, j = t & 127;
    float a = s_b1[k * 128 + j];
    for (int i = 0; i < 256; ++i) a += comb[i] * s_w1[k * 33024 + (2 + i) * 128 + j];
    cvec[t] = a;
  }
  __syncthreads();

  // ---- students: thread = (s, k) ----
  {
    int s2 = t >> 2, k = t & 3;
    float x0 = x[b * 256 + s2];
    float x1 = x[b * 256 + 128 + s2];
    float a0 = 0.f, a1 = 0.f;
    for (int j = 0; j < 128; ++j){
      float hk = dtanh(cvec[k * 128 + j] + x0 * sw01[k * 128 + j] + x1 * sw01[512 + k * 128 + j]);
      a0 += hk * sw2s[k * 256 + 2 * j];
      a1 += hk * sw2s[k * 256 + 2 * j + 1];
    }
    float mwk = mwls[k];
    float p0 = mwk * (a0 + s_b2[2 * k]);
    float p1 = mwk * (a1 + s_b2[2 * k + 1]);
    p0 += __shfl_xor(p0, 1); p0 += __shfl_xor(p0, 2);
    p1 += __shfl_xor(p1, 1); p1 += __shfl_xor(p1, 2);
    if (k == 0){
      out[b * 256 + s2]       = p0;
      out[b * 256 + 128 + s2] = p1;
    }
  }
}

extern "C" void kernel_launch(void* const* d_in, const int* in_sizes, int n_in,
                              void* d_out, int out_size, void* d_ws, size_t ws_size,
                              hipStream_t stream){
  (void)n_in; (void)d_ws; (void)ws_size; (void)out_size;
  hipFuncSetAttribute((const void*)fused_fp, hipFuncAttributeMaxDynamicSharedMemorySize, SMEM_BYTES);
  int B = in_sizes[1];  // timesteps count
  fused_fp<<<dim3(B), dim3(NTH), SMEM_BYTES, stream>>>(
      (const float*)d_in[0], (const int*)d_in[1], (const float*)d_in[2],
      (const float*)d_in[3], (const float*)d_in[4], (const float*)d_in[5], (const float*)d_in[6],
      (const float*)d_in[7], (const float*)d_in[8], (const float*)d_in[9], (const float*)d_in[10],
      (const float*)d_in[11], (const float*)d_in[12], (const float*)d_in[13], (const float*)d_in[14],
      (const float*)d_in[15], (const float*)d_in[16], (const float*)d_in[17], (const float*)d_in[18],
      (const float*)d_in[19], (const float*)d_in[20], (const float*)d_in[21], (const float*)d_in[22],
      (const float*)d_in[23], (const float*)d_in[24], (const float*)d_in[25], (const float*)d_in[26],
      (const float*)d_in[27], (const float*)d_in[28], (const float*)d_in[29], (const float*)d_in[30],
      (float*)d_out);
}

// Round 2
// 1768.295 us; speedup vs baseline: 4.1220x; 4.1220x over previous
//
#include <hip/hip_runtime.h>

typedef _Float16 hf;
typedef _Float16 hf4 __attribute__((ext_vector_type(4)));
typedef _Float16 hf8 __attribute__((ext_vector_type(8)));
typedef float f4 __attribute__((ext_vector_type(4)));

#define NTH 512
// LDS map (bytes)
#define ACT_OFF   0        // 32768: activations, packed 16x32 f16 tiles (m=s, k=f)
#define WB_OFF    32768    // 32768: staged packed weights
#define XB1_OFF   65536    // 32768: H1 / P / D+bias scratch
#define XB2_OFF   98304    // 32768: OB / F1 chunk / cond-phase f32 misc
#define QB_OFF    131072   // 8192  Q packed (m=s,k=d)
#define KB_OFF    139264   // 8192  K packed (m=s,k=d)
#define VT_OFF    147456   // 8192  V^T packed (m=d,k=s)
#define MISC_OFF  155648   // 784 f32: comb[256], mwls[16], lnp[512]
#define SMEM_BYTES 158784

// d_ws packed-weight layout (in halves)
#define WSH_QKV 0          // [l][h] 12288
#define WSH_WO  98304      // [l] 16384
#define WSH_FW1 131072     // [l][ch] 16384
#define WSH_FW2 196608     // [l][ch] 16384
#define WSH_CW2 262144     // 8192
#define WSH_TOTAL 270336

__device__ __forceinline__ float dsilu(float x){ return x / (1.f + __expf(-x)); }
__device__ __forceinline__ float dtanh(float x){
  float xc = fminf(fmaxf(x, -10.f), 10.f);
  float e = __expf(2.f * xc);
  return (e - 1.f) / (e + 1.f);
}

// ---------------- prep: pack f32 weights -> f16 A-fragment tile order ----------------
__global__ void prep_pack(const float* __restrict__ wqkv, const float* __restrict__ wo,
                          const float* __restrict__ fw1, const float* __restrict__ fw2,
                          const float* __restrict__ cw2, hf* __restrict__ ws){
  int idx = blockIdx.x * 256 + threadIdx.x;
  if (idx >= WSH_TOTAL) return;
  float v;
  if (idx < WSH_WO){                       // qkv per (layer, head): K=128, N=96
    int u = idx; int lh = u / 12288; int l = lh >> 2, h = lh & 3;
    int r = u % 12288; int tl = r >> 9; int lane = (r >> 3) & 63; int j = r & 7;
    int q = lane >> 4, c = lane & 15;
    int tn = tl >> 2, tk = tl & 3;
    int k = tk*32 + q*8 + j, nloc = tn*16 + c;
    int gcol = (nloc >> 5)*128 + h*32 + (nloc & 31);
    v = wqkv[l*49152 + k*384 + gcol];
  } else if (idx < WSH_FW1){               // wo: K=128, N=128
    int u = idx - WSH_WO; int l = u >> 14; int r = u & 16383;
    int tl = r >> 9; int lane = (r >> 3) & 63; int j = r & 7;
    int q = lane >> 4, c = lane & 15;
    int tn = tl >> 2, tk = tl & 3;
    v = wo[l*16384 + (tk*32 + q*8 + j)*128 + tn*16 + c];
  } else if (idx < WSH_FW2){               // fw1 chunk ch: cols ch*128..+127
    int u = idx - WSH_FW1; int lch = u >> 14; int l = lch >> 1, ch = lch & 1; int r = u & 16383;
    int tl = r >> 9; int lane = (r >> 3) & 63; int j = r & 7;
    int q = lane >> 4, c = lane & 15;
    int tn = tl >> 2, tk = tl & 3;
    v = fw1[l*32768 + (tk*32 + q*8 + j)*256 + ch*128 + tn*16 + c];
  } else if (idx < WSH_CW2){               // fw2 k-chunk ch: rows ch*128..+127
    int u = idx - WSH_FW2; int lch = u >> 14; int l = lch >> 1, ch = lch & 1; int r = u & 16383;
    int tl = r >> 9; int lane = (r >> 3) & 63; int j = r & 7;
    int q = lane >> 4, c = lane & 15;
    int tn = tl >> 2, tk = tl & 3;
    v = fw2[l*32768 + (ch*128 + tk*32 + q*8 + j)*128 + tn*16 + c];
  } else {                                 // c_w2: K=64, N=128
    int u = idx - WSH_CW2;
    int tl = u >> 9; int lane = (u >> 3) & 63; int j = u & 7;
    int q = lane >> 4, c = lane & 15;
    int tn = tl >> 1, tk = tl & 1;
    v = cw2[(tk*32 + q*8 + j)*128 + tn*16 + c];
  }
  ws[idx] = (hf)v;
}

// ---------------- helpers ----------------
template<int NHALVES>
__device__ __forceinline__ void copy_ws(hf* dst, const hf* src, int t){
  const hf8* s8 = (const hf8*)src; hf8* d8 = (hf8*)dst;
#pragma unroll
  for (int i = 0; i < NHALVES/8/NTH; ++i) d8[i*NTH + t] = s8[i*NTH + t];
}

// GEMM: D[f][s] tiles. A = packed weights (m=f_out, k), B = packed acts (m=s, k).
// wave handles 2 s-tiles (2sp, 2sp+1) x NT n-tiles (np*NT..+NT-1).
template<int KT, int NT>
__device__ __forceinline__ void gemmT(f4 (&acc)[2][NT], const hf* Ap, const hf* Bp,
                                      int sp, int np, int lane){
#pragma unroll
  for (int tk = 0; tk < KT; ++tk){
    hf8 b0 = *(const hf8*)(Bp + (((2*sp  )*KT + tk) << 9) + lane*8);
    hf8 b1 = *(const hf8*)(Bp + (((2*sp+1)*KT + tk) << 9) + lane*8);
#pragma unroll
    for (int jn = 0; jn < NT; ++jn){
      hf8 a = *(const hf8*)(Ap + (((np*NT + jn)*KT + tk) << 9) + lane*8);
      acc[0][jn] = __builtin_amdgcn_mfma_f32_16x16x32_f16(a, b0, acc[0][jn], 0, 0, 0);
      acc[1][jn] = __builtin_amdgcn_mfma_f32_16x16x32_f16(a, b1, acc[1][jn], 0, 0, 0);
    }
  }
}

// store D-tile (f = ft*16+q*4+r, s = ts*16+c) into packed(m=s,k=f) buffer, one b64
__device__ __forceinline__ void store_packed_b64(hf* dst, int KtilesOut, int ts, int ft,
                                                 f4 v, int q, int c){
  int tk = ft >> 1;
  int qp = ((ft & 1) << 1) + (q >> 1);
  int j0 = (q & 1) << 2;
  hf4 h; h[0] = (hf)v[0]; h[1] = (hf)v[1]; h[2] = (hf)v[2]; h[3] = (hf)v[3];
  *(hf4*)(dst + ((ts*KtilesOut + tk) << 9) + ((qp*16 + c) << 3) + j0) = h;
}

// ACT = LN(ACT + D) over f (=128) for each s; thread = s*4 + p
__device__ __forceinline__ void ln_pass(hf* A, const hf* Dh, const float* g, const float* bb, int t){
  int s = t >> 2, p = t & 3;
  float xr[4][8];
  int offs[4];
  float sum = 0.f, sq = 0.f;
#pragma unroll
  for (int tk = 0; tk < 4; ++tk){
    int off = (((s >> 4) * 4 + tk) << 9) + ((p * 16 + (s & 15)) << 3);
    offs[tk] = off;
    hf8 va = *(const hf8*)(A + off);
    hf8 vd = *(const hf8*)(Dh + off);
#pragma unroll
    for (int j = 0; j < 8; ++j){
      float x = (float)va[j] + (float)vd[j];
      xr[tk][j] = x; sum += x; sq += x * x;
    }
  }
  sum += __shfl_xor(sum, 1); sq += __shfl_xor(sq, 1);
  sum += __shfl_xor(sum, 2); sq += __shfl_xor(sq, 2);
  float mean = sum * (1.f/128.f);
  float rstd = rsqrtf(sq * (1.f/128.f) - mean*mean + 1e-5f);
#pragma unroll
  for (int tk = 0; tk < 4; ++tk){
    hf8 y;
#pragma unroll
    for (int j = 0; j < 8; ++j){
      int f = tk*32 + p*8 + j;
      y[j] = (hf)((xr[tk][j] - mean) * rstd * g[f] + bb[f]);
    }
    *(hf8*)(A + offs[tk]) = y;
  }
}

// ---------------- fused main kernel: one block per batch ----------------
__global__ __launch_bounds__(NTH, 2) void fused_fp(
    const float* __restrict__ x, const int* __restrict__ timesteps, const float* __restrict__ cond,
    const float* __restrict__ t_w1, const float* __restrict__ t_b1,
    const float* __restrict__ t_w2, const float* __restrict__ t_b2,
    const float* __restrict__ c_w1, const float* __restrict__ c_b1,
    const float* __restrict__ c_b2,
    const float* __restrict__ bqkv_g, const float* __restrict__ bo_g,
    const float* __restrict__ ln1g_g, const float* __restrict__ ln1b_g,
    const float* __restrict__ fb1_g, const float* __restrict__ fb2_g,
    const float* __restrict__ ln2g_g, const float* __restrict__ ln2b_g,
    const float* __restrict__ mw_w1, const float* __restrict__ mw_b1,
    const float* __restrict__ mw_w2, const float* __restrict__ mw_b2,
    const float* __restrict__ s_w1, const float* __restrict__ s_b1,
    const float* __restrict__ s_w2, const float* __restrict__ s_b2,
    const hf* __restrict__ wsp, float* __restrict__ out)
{
  extern __shared__ char smem[];
  hf* ACTh = (hf*)(smem + ACT_OFF);
  hf* WBh  = (hf*)(smem + WB_OFF);
  hf* XB1h = (hf*)(smem + XB1_OFF);
  hf* XB2h = (hf*)(smem + XB2_OFF);
  hf* QBh  = (hf*)(smem + QB_OFF);
  hf* KBh  = (hf*)(smem + KB_OFF);
  hf* VTh  = (hf*)(smem + VT_OFF);
  float* XB1f = (float*)(smem + XB1_OFF);
  float* XB2f = (float*)(smem + XB2_OFF);
  float* miscf = (float*)(smem + MISC_OFF);
  float* comb = miscf;          // 256
  float* mwls = miscf + 256;    // 16
  float* lnp  = miscf + 272;    // 512
  // cond-phase f32 (XB2): te[128], th[256], cst[768], cw1s[448]
  float* te = XB2f; float* th = XB2f + 128; float* cst = XB2f + 384; float* cw1s = XB2f + 1152;
  // student-phase f32 (QKV region)
  float* sw01 = (float*)(smem + QB_OFF);   // 1024
  float* sw2s = sw01 + 1024;               // 1024
  float* cvec = sw2s + 1024;               // 512

  const int b = blockIdx.x;
  const int t = threadIdx.x;
  const int w = t >> 6, lane = t & 63, q = lane >> 4, c = lane & 15;
  const int sp = w & 3, np = w >> 2;

  // ===== Phase 0: time features + cond staging =====
  if (t < 128){
    int i = t & 63;
    float f = __expf(-logf(10000.f) * (float)i * (1.f/64.f));
    float a = (float)timesteps[b] * f;
    te[t] = (t < 64) ? cosf(a) : sinf(a);
  }
  for (int idx = t; idx < 768; idx += NTH) cst[idx] = cond[b * 768 + idx];
  if (t < 384) cw1s[t] = c_w1[t];
  if (t < 64)  cw1s[384 + t] = c_b1[t];
  __syncthreads();

  // time MLP hidden; cond MLP layer1 -> H1 packed (XB1, Ktiles=2)
  if (t < 256){
    float a = t_b1[t];
    for (int i = 0; i < 128; ++i) a += te[i] * t_w1[i * 256 + t];
    th[t] = dsilu(a);
  }
  for (int idx = t; idx < 8192; idx += NTH){
    int s = idx >> 6, jf = idx & 63;
    float a = cw1s[384 + jf];
#pragma unroll
    for (int cc = 0; cc < 6; ++cc) a += cst[s * 6 + cc] * cw1s[cc * 64 + jf];
    XB1h[(((s >> 4)*2 + (jf >> 5)) << 9) + ((((jf & 31) >> 3)*16 + (s & 15)) << 3) + (jf & 7)] = (hf)dsilu(a);
  }
  __syncthreads();

  // time MLP out -> comb[0:128]; stage packed c_w2
  if (t < 128){
    float a = t_b2[t];
    for (int j = 0; j < 256; ++j) a += th[j] * t_w2[j * 128 + t];
    comb[t] = a;
  }
  copy_ws<8192>(WBh, wsp + WSH_CW2, t);
  __syncthreads();

  // cond MLP layer2 (MFMA) -> ACT packed
  {
    f4 acc[2][4]; 
#pragma unroll
    for (int i = 0; i < 2; ++i)
#pragma unroll
      for (int j = 0; j < 4; ++j){ f4 z = {0.f,0.f,0.f,0.f}; acc[i][j] = z; }
    gemmT<2,4>(acc, WBh, XB1h, sp, np, lane);
#pragma unroll
    for (int si = 0; si < 2; ++si)
#pragma unroll
      for (int jn = 0; jn < 4; ++jn){
        int ft = np*4 + jn, ts = 2*sp + si;
        f4 v = acc[si][jn];
#pragma unroll
        for (int r = 0; r < 4; ++r) v[r] = dsilu(v[r] + c_b2[ft*16 + q*4 + r]);
        store_packed_b64(ACTh, 4, ts, ft, v, q, c);
      }
  }
  __syncthreads();

  // ===== 2 transformer layers =====
  for (int l = 0; l < 2; ++l){
    if (t < 128){
      lnp[t]       = ln1g_g[l*128 + t];
      lnp[128 + t] = ln1b_g[l*128 + t];
      lnp[256 + t] = ln2g_g[l*128 + t];
      lnp[384 + t] = ln2b_g[l*128 + t];
    }
    f4 oacc[8];
#pragma unroll
    for (int i = 0; i < 8; ++i){ f4 z = {0.f,0.f,0.f,0.f}; oacc[i] = z; }

    for (int h = 0; h < 4; ++h){
      copy_ws<12288>(WBh, wsp + WSH_QKV + (l*4 + h)*12288, t);
      __syncthreads();
      // QKV GEMM (N=96): 2s x 3n
      {
        f4 acc[2][3];
#pragma unroll
        for (int i = 0; i < 2; ++i)
#pragma unroll
          for (int j = 0; j < 3; ++j){ f4 z = {0.f,0.f,0.f,0.f}; acc[i][j] = z; }
        gemmT<4,3>(acc, WBh, ACTh, sp, np, lane);
#pragma unroll
        for (int si = 0; si < 2; ++si)
#pragma unroll
          for (int jn = 0; jn < 3; ++jn){
            int ft = np*3 + jn, ts = 2*sp + si;
            int sel = ft >> 1;
            f4 v = acc[si][jn];
#pragma unroll
            for (int r = 0; r < 4; ++r)
              v[r] += bqkv_g[l*384 + sel*128 + h*32 + ((ft & 1)*16 + q*4 + r)];
            if (sel == 0){
#pragma unroll
              for (int r = 0; r < 4; ++r) v[r] *= 0.17677669529663687f;
              store_packed_b64(QBh, 1, ts, ft, v, q, c);
            } else if (sel == 1){
              store_packed_b64(KBh, 1, ts, ft - 2, v, q, c);
            } else {
              int td = ft - 4;
              int qp = ((ts & 1) << 1) + (c >> 3);
              hf* pb = VTh + ((td*4 + (ts >> 1)) << 9) + (c & 7);
#pragma unroll
              for (int r = 0; r < 4; ++r) pb[(qp*16 + q*4 + r) << 3] = (hf)v[r];
            }
          }
      }
      __syncthreads();
      // scores + softmax + P write (wave w owns q-tile w)
      {
        hf8 af = *(const hf8*)(QBh + (w << 9) + lane*8);
        f4 sc[8];
#pragma unroll
        for (int kst = 0; kst < 8; ++kst){
          hf8 bf = *(const hf8*)(KBh + (kst << 9) + lane*8);
          f4 z = {0.f,0.f,0.f,0.f};
          sc[kst] = __builtin_amdgcn_mfma_f32_16x16x32_f16(af, bf, z, 0, 0, 0);
        }
        float mr[4] = {-1e30f, -1e30f, -1e30f, -1e30f};
#pragma unroll
        for (int kst = 0; kst < 8; ++kst)
#pragma unroll
          for (int r = 0; r < 4; ++r) mr[r] = fmaxf(mr[r], sc[kst][r]);
#pragma unroll
        for (int r = 0; r < 4; ++r){
          mr[r] = fmaxf(mr[r], __shfl_xor(mr[r], 1));
          mr[r] = fmaxf(mr[r], __shfl_xor(mr[r], 2));
          mr[r] = fmaxf(mr[r], __shfl_xor(mr[r], 4));
          mr[r] = fmaxf(mr[r], __shfl_xor(mr[r], 8));
        }
        float ls[4] = {0.f, 0.f, 0.f, 0.f};
#pragma unroll
        for (int kst = 0; kst < 8; ++kst)
#pragma unroll
          for (int r = 0; r < 4; ++r){
            float e = __expf(sc[kst][r] - mr[r]);
            sc[kst][r] = e; ls[r] += e;
          }
#pragma unroll
        for (int r = 0; r < 4; ++r){
          ls[r] += __shfl_xor(ls[r], 1);
          ls[r] += __shfl_xor(ls[r], 2);
          ls[r] += __shfl_xor(ls[r], 4);
          ls[r] += __shfl_xor(ls[r], 8);
          ls[r] = 1.f / ls[r];
        }
#pragma unroll
        for (int kst = 0; kst < 8; ++kst){
          int qp = ((kst & 1) << 1) + (c >> 3);
          hf* pb = XB1h + ((w*4 + (kst >> 1)) << 9) + (c & 7);
#pragma unroll
          for (int r = 0; r < 4; ++r)
            pb[(qp*16 + q*4 + r) << 3] = (hf)(sc[kst][r] * ls[r]);
        }
      }
      // AV (same-wave P, barrier-free vs scores); accumulate into oacc
      {
#pragma unroll
        for (int ks = 0; ks < 4; ++ks){
          hf8 bp = *(const hf8*)(XB1h + ((w*4 + ks) << 9) + lane*8);
          hf8 a0 = *(const hf8*)(VTh + ((     ks) << 9) + lane*8);
          hf8 a1 = *(const hf8*)(VTh + ((4 +  ks) << 9) + lane*8);
          oacc[2*h]     = __builtin_amdgcn_mfma_f32_16x16x32_f16(a0, bp, oacc[2*h],     0, 0, 0);
          oacc[2*h + 1] = __builtin_amdgcn_mfma_f32_16x16x32_f16(a1, bp, oacc[2*h + 1], 0, 0, 0);
        }
      }
    } // heads

    // write attention output OB -> XB2 packed (wave w owns s-tile w)
#pragma unroll
    for (int ft = 0; ft < 8; ++ft) store_packed_b64(XB2h, 4, w, ft, oacc[ft], q, c);
    __syncthreads();

    // WO projection
    copy_ws<16384>(WBh, wsp + WSH_WO + l*16384, t);
    __syncthreads();
    {
      f4 acc[2][4];
#pragma unroll
      for (int i = 0; i < 2; ++i)
#pragma unroll
        for (int j = 0; j < 4; ++j){ f4 z = {0.f,0.f,0.f,0.f}; acc[i][j] = z; }
      gemmT<4,4>(acc, WBh, XB2h, sp, np, lane);
#pragma unroll
      for (int si = 0; si < 2; ++si)
#pragma unroll
        for (int jn = 0; jn < 4; ++jn){
          int ft = np*4 + jn, ts = 2*sp + si;
          f4 v = acc[si][jn];
#pragma unroll
          for (int r = 0; r < 4; ++r) v[r] += bo_g[l*128 + ft*16 + q*4 + r];
          store_packed_b64(XB1h, 4, ts, ft, v, q, c);
        }
    }
    __syncthreads();
    ln_pass(ACTh, XB1h, lnp, lnp + 128, t);
    __syncthreads();

    // FFN: two 128-col chunks; FFN2 accumulates in regs
    {
      f4 facc[2][4];
#pragma unroll
      for (int i = 0; i < 2; ++i)
#pragma unroll
        for (int j = 0; j < 4; ++j){ f4 z = {0.f,0.f,0.f,0.f}; facc[i][j] = z; }
      for (int ch = 0; ch < 2; ++ch){
        copy_ws<16384>(WBh, wsp + WSH_FW1 + (l*2 + ch)*16384, t);
        __syncthreads();
        {
          f4 acc[2][4];
#pragma unroll
          for (int i = 0; i < 2; ++i)
#pragma unroll
            for (int j = 0; j < 4; ++j){ f4 z = {0.f,0.f,0.f,0.f}; acc[i][j] = z; }
          gemmT<4,4>(acc, WBh, ACTh, sp, np, lane);
#pragma unroll
          for (int si = 0; si < 2; ++si)
#pragma unroll
            for (int jn = 0; jn < 4; ++jn){
              int ft = np*4 + jn, ts = 2*sp + si;
              f4 v = acc[si][jn];
#pragma unroll
              for (int r = 0; r < 4; ++r)
                v[r] = fmaxf(v[r] + fb1_g[l*256 + ch*128 + ft*16 + q*4 + r], 0.f);
              store_packed_b64(XB2h, 4, ts, ft, v, q, c);
            }
        }
        __syncthreads();
        copy_ws<16384>(WBh, wsp + WSH_FW2 + (l*2 + ch)*16384, t);
        __syncthreads();
        gemmT<4,4>(facc, WBh, XB2h, sp, np, lane);
        __syncthreads();
      }
#pragma unroll
      for (int si = 0; si < 2; ++si)
#pragma unroll
        for (int jn = 0; jn < 4; ++jn){
          int ft = np*4 + jn, ts = 2*sp + si;
          f4 v = facc[si][jn];
#pragma unroll
          for (int r = 0; r < 4; ++r) v[r] += fb2_g[l*128 + ft*16 + q*4 + r];
          store_packed_b64(XB1h, 4, ts, ft, v, q, c);
        }
    }
    __syncthreads();
    ln_pass(ACTh, XB1h, lnp + 256, lnp + 384, t);
    __syncthreads();
  } // layers

  // ===== cond_emb mean -> comb[128:256] =====
  {
    int f = t & 127, sg = t >> 7;
    float a = 0.f;
    for (int s2 = sg*32; s2 < sg*32 + 32; ++s2)
      a += (float)ACTh[(((s2 >> 4)*4 + (f >> 5)) << 9) + ((((f & 31) >> 3)*16 + (s2 & 15)) << 3) + (f & 7)];
    XB1f[t] = a;
  }
  __syncthreads();
  if (t < 128) comb[128 + t] = (XB1f[t] + XB1f[128 + t] + XB1f[256 + t] + XB1f[384 + t]) * (1.f/128.f);
  __syncthreads();

  // mixture hidden + stage student weights
  if (t < 128){
    float a = mw_b1[t];
    for (int i = 0; i < 256; ++i) a += comb[i] * mw_w1[i * 128 + t];
    XB1f[512 + t] = dsilu(a);
  }
  {
    int k = t >> 7, j = t & 127;
    sw01[t]       = s_w1[k * 33024 + j];
    sw01[512 + t] = s_w1[k * 33024 + 128 + j];
  }
  for (int idx = t; idx < 1024; idx += NTH) sw2s[idx] = s_w2[idx];
  __syncthreads();

  if (t < 4){
    float a = mw_b2[t];
    for (int j = 0; j < 128; ++j) a += XB1f[512 + j] * mw_w2[j * 4 + t];
    mwls[4 + t] = a;
  }
  __syncthreads();
  if (t == 0){
    float mx = fmaxf(fmaxf(mwls[4], mwls[5]), fmaxf(mwls[6], mwls[7]));
    float e0 = __expf(mwls[4] - mx), e1 = __expf(mwls[5] - mx);
    float e2 = __expf(mwls[6] - mx), e3 = __expf(mwls[7] - mx);
    float rs = 1.f / (e0 + e1 + e2 + e3);
    mwls[0] = e0 * rs; mwls[1] = e1 * rs; mwls[2] = e2 * rs; mwls[3] = e3 * rs;
  }
  {
    int k = t >> 7, j = t & 127;
    float a = s_b1[k * 128 + j];
    for (int i = 0; i < 256; ++i) a += comb[i] * s_w1[k * 33024 + (2 + i) * 128 + j];
    cvec[t] = a;
  }
  __syncthreads();

  // students: thread = (s, k)
  {
    int s2 = t >> 2, k = t & 3;
    float x0 = x[b * 256 + s2];
    float x1 = x[b * 256 + 128 + s2];
    float a0 = 0.f, a1 = 0.f;
    for (int j = 0; j < 128; ++j){
      float hk = dtanh(cvec[k * 128 + j] + x0 * sw01[k * 128 + j] + x1 * sw01[512 + k * 128 + j]);
      a0 += hk * sw2s[k * 256 + 2 * j];
      a1 += hk * sw2s[k * 256 + 2 * j + 1];
    }
    float mwk = mwls[k];
    float p0 = mwk * (a0 + s_b2[2 * k]);
    float p1 = mwk * (a1 + s_b2[2 * k + 1]);
    p0 += __shfl_xor(p0, 1); p0 += __shfl_xor(p0, 2);
    p1 += __shfl_xor(p1, 1); p1 += __shfl_xor(p1, 2);
    if (k == 0){
      out[b * 256 + s2]       = p0;
      out[b * 256 + 128 + s2] = p1;
    }
  }
}

extern "C" void kernel_launch(void* const* d_in, const int* in_sizes, int n_in,
                              void* d_out, int out_size, void* d_ws, size_t ws_size,
                              hipStream_t stream){
  (void)n_in; (void)ws_size; (void)out_size;
  hipFuncSetAttribute((const void*)fused_fp, hipFuncAttributeMaxDynamicSharedMemorySize, SMEM_BYTES);
  int B = in_sizes[1];
  hf* wsp = (hf*)d_ws;
  prep_pack<<<dim3((WSH_TOTAL + 255) / 256), dim3(256), 0, stream>>>(
      (const float*)d_in[11], (const float*)d_in[13], (const float*)d_in[17],
      (const float*)d_in[19], (const float*)d_in[9], wsp);
  fused_fp<<<dim3(B), dim3(NTH), SMEM_BYTES, stream>>>(
      (const float*)d_in[0], (const int*)d_in[1], (const float*)d_in[2],
      (const float*)d_in[3], (const float*)d_in[4], (const float*)d_in[5], (const float*)d_in[6],
      (const float*)d_in[7], (const float*)d_in[8], (const float*)d_in[10],
      (const float*)d_in[12], (const float*)d_in[14],
      (const float*)d_in[15], (const float*)d_in[16],
      (const float*)d_in[18], (const float*)d_in[20],
      (const float*)d_in[21], (const float*)d_in[22],
      (const float*)d_in[23], (const float*)d_in[24], (const float*)d_in[25], (const float*)d_in[26],
      (const float*)d_in[27], (const float*)d_in[28], (const float*)d_in[29], (const float*)d_in[30],
      wsp, (float*)d_out);
}